// Round 11
// baseline (891.864 us; speedup 1.0000x reference)
//
#include <hip/hip_runtime.h>

#define EMB 100
#define XSTRIDE 52       // bf16 X row stride in dwords (16B-aligned rows)
#define Y8DW 32          // fp8 Y row stride in dwords (128 B, line-aligned)
#define BSHIFT 8         // bucket = row >> 8  (256 rows/bucket)
#define BROWS 256
#define MAXBUCK 1024
#define CAP 9216         // fixed part-segment capacity per bucket (11-sigma slack)
#define CHUNK 4096       // edges per workgroup in partition
#define EPT (CHUNK / 256)

typedef __attribute__((ext_vector_type(8))) short short8;
typedef __attribute__((ext_vector_type(4))) float f32x4;
typedef __attribute__((ext_vector_type(2))) float f2v;

// ---- bf16 helpers ----
__device__ __forceinline__ unsigned packbf(float a, float b) {
    unsigned ua = __float_as_uint(a), ub = __float_as_uint(b);
    unsigned ra = (ua + 0x7FFFu + ((ua >> 16) & 1u)) >> 16;   // RNE
    unsigned rb = (ub + 0x7FFFu + ((ub >> 16) & 1u)) >> 16;
    return ra | (rb << 16);
}

// ---- fp8 e4m3 (OCP) helpers ----
__device__ __forceinline__ unsigned char f32_to_fp8(float f) {
    unsigned u = __float_as_uint(f);
    unsigned s = (u >> 24) & 0x80u;
    unsigned mag = u & 0x7FFFFFFFu;
    if (mag >= 0x43E00000u) return (unsigned char)(s | 0x7Eu);      // clamp 448
    if (mag < 0x3C800000u) {                                        // subnormal
        int r = __float2int_rn(__uint_as_float(mag) * 512.f);
        return (unsigned char)(s | (unsigned)r);
    }
    unsigned r = mag + 0x7FFFFu + ((mag >> 20) & 1u);               // RNE at bit 20
    unsigned e = r >> 23, m = (r >> 20) & 7u;
    return (unsigned char)(s | ((e - 120u) << 3) | m);
}

__device__ __forceinline__ unsigned pack4_fp8(float a0, float a1, float a2, float a3) {
#if __has_builtin(__builtin_amdgcn_cvt_pk_fp8_f32)
    int lo = __builtin_amdgcn_cvt_pk_fp8_f32(a0, a1, 0, false);
    return (unsigned)__builtin_amdgcn_cvt_pk_fp8_f32(a2, a3, lo, true);
#else
    return (unsigned)f32_to_fp8(a0) | ((unsigned)f32_to_fp8(a1) << 8) |
           ((unsigned)f32_to_fp8(a2) << 16) | ((unsigned)f32_to_fp8(a3) << 24);
#endif
}

__device__ __forceinline__ void fma_fp8x4(unsigned g, float v,
                                          float& a0, float& a1, float& a2, float& a3) {
#if __has_builtin(__builtin_amdgcn_cvt_pk_f32_fp8)
    f2v lo = __builtin_amdgcn_cvt_pk_f32_fp8((int)g, false);
    f2v hi = __builtin_amdgcn_cvt_pk_f32_fp8((int)g, true);
    a0 = fmaf(v, lo[0], a0); a1 = fmaf(v, lo[1], a1);
    a2 = fmaf(v, hi[0], a2); a3 = fmaf(v, hi[1], a3);
#else
    float o[4];
#pragma unroll
    for (int d = 0; d < 4; ++d) {
        unsigned b = (g >> (8 * d)) & 0xFFu;
        unsigned e = (b >> 3) & 15u, m = b & 7u;
        float val = e ? __uint_as_float(((e + 120u) << 23) | (m << 20))
                      : (float)m * (1.f / 512.f);
        o[d] = (b & 0x80u) ? -val : val;
    }
    a0 = fmaf(v, o[0], a0); a1 = fmaf(v, o[1], a1);
    a2 = fmaf(v, o[2], a2); a3 = fmaf(v, o[3], a3);
#endif
}

// ---------------- partition into fixed-capacity row-bucket segments ----------
// One pass over COO. Pass-1 LDS-hist atomic's return value IS the edge's
// within-(chunk,bucket) rank (reused for stage placement -> no 2nd atomic
// pass). Stage is bucket-sorted in LDS, then swept out coalesced into
// part[b*CAP + global_rank]. bucket_cnt[b] ends at the bucket's total count.
__global__ __launch_bounds__(256) void k_partition(const int* __restrict__ rows,
                                                   const int* __restrict__ cols,
                                                   const float* __restrict__ vals,
                                                   int* __restrict__ bucket_cnt,
                                                   int2* __restrict__ part,
                                                   int E, int nbuck) {
    __shared__ int hist[MAXBUCK];
    __shared__ int loc[MAXBUCK];
    __shared__ int base_s[MAXBUCK];
    __shared__ int scan256[256];
    __shared__ int2 stage[CHUNK];      // 32 KB bucket-sorted staging
    int tid = threadIdx.x;
    int base = blockIdx.x * CHUNK;
    int nE = E - base; if (nE > CHUNK) nE = CHUNK;

    for (int s = tid; s < nbuck; s += 256) hist[s] = 0;
    __syncthreads();

    int r_[EPT]; unsigned cv_[EPT]; int rk_[EPT];
#pragma unroll
    for (int k = 0; k < EPT; ++k) {
        int o = tid + k * 256;
        if (o < nE) {
            int i = base + o;
            int r = rows[i];
            unsigned q = (unsigned)__float2int_rn(vals[i] * 16383.f);
            r_[k] = r;
            cv_[k] = (unsigned)cols[i] | (q << 18);
            rk_[k] = atomicAdd(&hist[r >> BSHIFT], 1);   // rank within (chunk,bucket)
        } else r_[k] = -1;
    }
    __syncthreads();

    // reserve global space per bucket
    for (int s = tid; s < nbuck; s += 256)
        base_s[s] = hist[s] ? atomicAdd(&bucket_cnt[s], hist[s]) : 0;

    // exclusive scan of hist -> loc (4 buckets per thread)
    int s4 = tid * 4;
    int h0 = (s4     < nbuck) ? hist[s4]     : 0;
    int h1 = (s4 + 1 < nbuck) ? hist[s4 + 1] : 0;
    int h2 = (s4 + 2 < nbuck) ? hist[s4 + 2] : 0;
    int h3 = (s4 + 3 < nbuck) ? hist[s4 + 3] : 0;
    int tot = h0 + h1 + h2 + h3;
    scan256[tid] = tot;
    __syncthreads();
    for (int off = 1; off < 256; off <<= 1) {
        int t = (tid >= off) ? scan256[tid - off] : 0;
        __syncthreads();
        scan256[tid] += t;
        __syncthreads();
    }
    int excl = scan256[tid] - tot;
    if (s4     < nbuck) loc[s4]     = excl;
    if (s4 + 1 < nbuck) loc[s4 + 1] = excl + h0;
    if (s4 + 2 < nbuck) loc[s4 + 2] = excl + h0 + h1;
    if (s4 + 3 < nbuck) loc[s4 + 3] = excl + h0 + h1 + h2;
    __syncthreads();

    // place bucket-sorted into LDS stage using pass-1 ranks
#pragma unroll
    for (int k = 0; k < EPT; ++k) {
        if (r_[k] >= 0) {
            int b = r_[k] >> BSHIFT;
            stage[loc[b] + rk_[k]] = make_int2(r_[k], (int)cv_[k]);
        }
    }
    __syncthreads();

    // linear sweep -> coalesced contiguous per-bucket runs in part segments
    for (int k = tid; k < nE; k += 256) {
        int2 e = stage[k];
        int b = e.x >> BSHIFT;
        int pos = base_s[b] + (k - loc[b]);
        if (pos < CAP)   // statistically impossible overflow guard
            part[(size_t)b * CAP + pos] = e;
    }
}

// ---------------- exclusive scan of bucket counts -> csr bases ---------------
__global__ __launch_bounds__(1024) void k_scan2(const int* __restrict__ cnt,
                                                int* __restrict__ basearr, int nb) {
    __shared__ int tmp[1024];
    int v = (threadIdx.x < nb) ? cnt[threadIdx.x] : 0;
    tmp[threadIdx.x] = v;
    __syncthreads();
    for (int off = 1; off < 1024; off <<= 1) {
        int t = (threadIdx.x >= off) ? tmp[threadIdx.x - off] : 0;
        __syncthreads();
        tmp[threadIdx.x] += t;
        __syncthreads();
    }
    if (threadIdx.x < nb) basearr[threadIdx.x] = tmp[threadIdx.x] - v; // exclusive
}

// ---------------- per-bucket CSR finalize ----------------
__global__ __launch_bounds__(256) void k_build_csr(const int2* __restrict__ part,
                                                   const int* __restrict__ bucket_cnt,
                                                   const int* __restrict__ bucket_base,
                                                   int* __restrict__ row_ptr,
                                                   unsigned* __restrict__ csr,
                                                   int N, int E) {
    __shared__ int cnt[BROWS];
    __shared__ int scn[BROWS];
    __shared__ int cur[BROWS];
    int b = blockIdx.x;
    int tid = threadIdx.x;
    int cntb = bucket_cnt[b];
    const int2* seg = part + (size_t)b * CAP;
    int cbase = bucket_base[b];
    int rowbase = b << BSHIFT;

    cnt[tid] = 0;
    __syncthreads();
    for (int i = tid; i < cntb; i += 256)
        atomicAdd(&cnt[seg[i].x - rowbase], 1);
    __syncthreads();
    int v = cnt[tid];
    scn[tid] = v;
    __syncthreads();
    for (int off = 1; off < 256; off <<= 1) {
        int t = (tid >= off) ? scn[tid - off] : 0;
        __syncthreads();
        scn[tid] += t;
        __syncthreads();
    }
    int rp = cbase + scn[tid] - v;            // global exclusive
    if (rowbase + tid < N) row_ptr[rowbase + tid] = rp;
    cur[tid] = rp;
    if (b == 0 && tid == 0) row_ptr[N] = E;
    __syncthreads();
    for (int i = tid; i < cntb; i += 256) {
        int2 e = seg[i];
        int pos = atomicAdd(&cur[e.x - rowbase], 1);
        csr[pos] = (unsigned)e.y;
    }
}

// ---------------- MFMA GEMM: Y8[r][e] = fp8( sum_d X[r][d] * W[e][d] ) --------
// Swapped operands: lane holds row's 4 consecutive e -> 1 packed dword store.
// Zeroes the FULL row pad (dwords 25..31) so spmm's gathers are clean.
template <bool F32SRC>
__global__ __launch_bounds__(256) void k_gemm_mfma(const void* __restrict__ Xv,
                                                   const float* __restrict__ W,
                                                   unsigned* __restrict__ Y8,
                                                   int nTiles, int N) {
    __shared__ uint4 Bf[28][64];   // [nt*4+ks][lane]  W fragments (bf16)
    int tid = threadIdx.x;
#pragma unroll
    for (int it = 0; it < 7; ++it) {
        int id = it * 256 + tid;
        int fs = id >> 6, lane = id & 63;
        int nt = fs >> 2, ks = fs & 3;
        int e = nt * 16 + (lane & 15);
        int dbase = ks * 32 + (lane >> 4) * 8;
        float w[8];
#pragma unroll
        for (int j = 0; j < 8; ++j) {
            int d = dbase + j;
            w[j] = (e < EMB && d < EMB) ? W[e * EMB + d] : 0.f;
        }
        uint4 u;
        u.x = packbf(w[0], w[1]); u.y = packbf(w[2], w[3]);
        u.z = packbf(w[4], w[5]); u.w = packbf(w[6], w[7]);
        Bf[fs][lane] = u;
    }
    __syncthreads();

    int wid = (blockIdx.x * 256 + tid) >> 6;
    int nWaves = gridDim.x * 4;
    int lane = tid & 63;
    int m = lane & 15, kg = lane >> 4;

    for (int tile = wid; tile < nTiles; tile += nWaves) {
        int rowbase = tile * 16;
        int arow = rowbase + m; if (arow >= N) arow = N - 1;   // clamp
        uint4 a[4];
        if (F32SRC) {
            const float* xr = (const float*)Xv + (size_t)arow * EMB;
#pragma unroll
            for (int ks = 0; ks < 3; ++ks) {
                float4 v0 = *(const float4*)(xr + ks * 32 + kg * 8);
                float4 v1 = *(const float4*)(xr + ks * 32 + kg * 8 + 4);
                a[ks] = make_uint4(packbf(v0.x, v0.y), packbf(v0.z, v0.w),
                                   packbf(v1.x, v1.y), packbf(v1.z, v1.w));
            }
            uint4 t = make_uint4(0, 0, 0, 0);
            if (kg == 0) { float4 v = *(const float4*)(xr + 96);
                           t.x = packbf(v.x, v.y); t.y = packbf(v.z, v.w); }
            a[3] = t;
        } else {
            const unsigned* xr = (const unsigned*)Xv + (size_t)arow * XSTRIDE;
#pragma unroll
            for (int ks = 0; ks < 3; ++ks)
                a[ks] = *(const uint4*)(xr + ks * 16 + kg * 4);
            uint4 t = make_uint4(0, 0, 0, 0);
            if (kg == 0) { uint2 v = *(const uint2*)(xr + 48); t.x = v.x; t.y = v.y; }
            a[3] = t;
        }

        f32x4 acc[7];
#pragma unroll
        for (int nt = 0; nt < 7; ++nt) acc[nt] = (f32x4){0.f, 0.f, 0.f, 0.f};
#pragma unroll
        for (int ks = 0; ks < 4; ++ks) {
            short8 av = __builtin_bit_cast(short8, a[ks]);
#pragma unroll
            for (int nt = 0; nt < 7; ++nt) {
                short8 bv = __builtin_bit_cast(short8, Bf[nt * 4 + ks][lane]);
                acc[nt] = __builtin_amdgcn_mfma_f32_16x16x32_bf16(bv, av, acc[nt], 0, 0, 0);
            }
        }
        int rr = rowbase + m;
        if (rr < N) {
            unsigned* yrow = Y8 + ((size_t)rr << 5) + kg;
#pragma unroll
            for (int nt = 0; nt < 6; ++nt)
                yrow[nt * 4] = pack4_fp8(acc[nt][0], acc[nt][1], acc[nt][2], acc[nt][3]);
            if (kg == 0)
                yrow[24] = pack4_fp8(acc[6][0], acc[6][1], acc[6][2], acc[6][3]);
            else
                yrow[24] = 0;   // dwords 25,26,27 = 0
            yrow[28] = 0;       // dwords 28..31 = 0
        }
    }
}

// ---------------- SpMM + norm + mean-accumulate (fp8 dwordx2 gather) ---------
// One wave per row; 4 groups x 16 lanes; group g takes edges j==g mod 4;
// lane lg gathers 8 B (dims 8lg..8lg+7). Full 32-edge blocks run UNCHECKED
// (8 gathers in flight); tail <=31 edges checked. dq deferred to epilogue.
__global__ __launch_bounds__(256) void k_spmm_norm(const int* __restrict__ row_ptr,
                                                   const unsigned* __restrict__ csr,
                                                   const unsigned* __restrict__ Y8,
                                                   unsigned* __restrict__ Xout,
                                                   float* __restrict__ Out,
                                                   const float* __restrict__ prev,
                                                   float pscale, float scale,
                                                   int writeX, int N) {
    int wave = (blockIdx.x * 256 + threadIdx.x) >> 6;
    int lane = threadIdx.x & 63;
    if (wave >= N) return;
    int g = lane >> 4, lg = lane & 15;
    int beg = row_ptr[wave], end = row_ptr[wave + 1];
    const float dq = 1.0f / 16383.f;
    float a0 = 0.f, a1 = 0.f, a2 = 0.f, a3 = 0.f;
    float a4 = 0.f, a5 = 0.f, a6 = 0.f, a7 = 0.f;
    const unsigned char* Yb = (const unsigned char*)Y8;

    int cnt = end - beg;
    int jmax = beg + (cnt & ~31);
    int j = beg;
    for (; j < jmax; j += 32) {
#pragma unroll
        for (int t = 0; t < 8; ++t) {
            unsigned u = __builtin_nontemporal_load(&csr[j + t * 4 + g]);
            float v = (float)(u >> 18);
            uint2 gg = *(const uint2*)(Yb + ((size_t)(u & 0x3FFFFu) << 7) + lg * 8);
            fma_fp8x4(gg.x, v, a0, a1, a2, a3);
            fma_fp8x4(gg.y, v, a4, a5, a6, a7);
        }
    }
    for (; j < end; j += 4) {           // tail: up to 31 edges
        int je = j + g;
        bool ok = je < end;
        unsigned u = csr[ok ? je : beg];
        float v = ok ? (float)(u >> 18) : 0.f;
        uint2 gg = *(const uint2*)(Yb + ((size_t)(u & 0x3FFFFu) << 7) + lg * 8);
        fma_fp8x4(gg.x, v, a0, a1, a2, a3);
        fma_fp8x4(gg.y, v, a4, a5, a6, a7);
    }

    // combine the 4 groups (same lg across groups holds same dims)
    a0 += __shfl_xor(a0, 16, 64); a0 += __shfl_xor(a0, 32, 64);
    a1 += __shfl_xor(a1, 16, 64); a1 += __shfl_xor(a1, 32, 64);
    a2 += __shfl_xor(a2, 16, 64); a2 += __shfl_xor(a2, 32, 64);
    a3 += __shfl_xor(a3, 16, 64); a3 += __shfl_xor(a3, 32, 64);
    a4 += __shfl_xor(a4, 16, 64); a4 += __shfl_xor(a4, 32, 64);
    a5 += __shfl_xor(a5, 16, 64); a5 += __shfl_xor(a5, 32, 64);
    a6 += __shfl_xor(a6, 16, 64); a6 += __shfl_xor(a6, 32, 64);
    a7 += __shfl_xor(a7, 16, 64); a7 += __shfl_xor(a7, 32, 64);

    float ss = 0.f;
    if (lg < 13) {
        ss = a0 * a0 + a1 * a1 + a2 * a2 + a3 * a3 +
             a4 * a4 + a5 * a5 + a6 * a6 + a7 * a7;   // lane12 a4..a7==0 (pad zeroed)
    }
#pragma unroll
    for (int off = 1; off < 16; off <<= 1) ss += __shfl_xor(ss, off, 64);
    // a[] are scaled by 16383; ||x|| = sqrt(ss)*dq -> fold dq into so
    float so = scale / fmaxf(sqrtf(ss), 1e-8f);

    if (lane < 13) {   // group 0 writes; lane == lg
        if (writeX) {
            unsigned* xp = Xout + (size_t)wave * XSTRIDE + lane * 4;
            if (lane < 12) {
                uint4 xw;
                xw.x = packbf(a0 * dq, a1 * dq); xw.y = packbf(a2 * dq, a3 * dq);
                xw.z = packbf(a4 * dq, a5 * dq); xw.w = packbf(a6 * dq, a7 * dq);
                *(uint4*)xp = xw;
            } else {
                uint2 xw; xw.x = packbf(a0 * dq, a1 * dq); xw.y = packbf(a2 * dq, a3 * dq);
                *(uint2*)xp = xw;
            }
        }
        const float* pr = prev + (size_t)wave * EMB + lane * 8;
        float* op = Out + (size_t)wave * EMB + lane * 8;
        float4 p0 = *(const float4*)pr;
        float4 o0;
        o0.x = fmaf(a0, so, p0.x * pscale);
        o0.y = fmaf(a1, so, p0.y * pscale);
        o0.z = fmaf(a2, so, p0.z * pscale);
        o0.w = fmaf(a3, so, p0.w * pscale);
        *(float4*)op = o0;
        if (lane < 12) {
            float4 p1 = *(const float4*)(pr + 4);
            float4 o1;
            o1.x = fmaf(a4, so, p1.x * pscale);
            o1.y = fmaf(a5, so, p1.y * pscale);
            o1.z = fmaf(a6, so, p1.z * pscale);
            o1.w = fmaf(a7, so, p1.w * pscale);
            *(float4*)(op + 4) = o1;
        }
    }
}

extern "C" void kernel_launch(void* const* d_in, const int* in_sizes, int n_in,
                              void* d_out, int out_size, void* d_ws, size_t ws_size,
                              hipStream_t stream) {
    const float* emb   = (const float*)d_in[0];
    const float* avals = (const float*)d_in[1];
    const float* wts   = (const float*)d_in[2];
    const int*   arows = (const int*)d_in[3];
    const int*   acols = (const int*)d_in[4];

    const int N = in_sizes[0] / EMB;
    const int E = in_sizes[1];
    const int L = in_sizes[2] / (EMB * EMB);
    const float scale = 1.0f / (float)(L + 1);
    const int nbuck = (N + BROWS - 1) >> BSHIFT;

    // workspace layout (dwords). part (nbuck*CAP int2) aliases Y8+bufX
    // (57.7 MB <= 67.2 MB; part is dead before the first GEMM writes Y8).
    unsigned* Y8      = (unsigned*)d_ws;                     // N*Y8DW (fp8 rows)
    unsigned* bufX    = Y8 + (size_t)N * Y8DW;               // N*XSTRIDE (bf16)
    int* row_ptr      = (int*)(bufX + (size_t)N * XSTRIDE);  // N+2
    int* bucket_cnt   = row_ptr + (N + 2);                   // MAXBUCK
    int* bucket_base  = bucket_cnt + MAXBUCK;                // MAXBUCK
    unsigned* csr     = (unsigned*)(bucket_base + MAXBUCK);  // E
    int2* part        = (int2*)d_ws;                         // nbuck*CAP (aliased)
    float* out = (float*)d_out;

    const int nchunk = (E + CHUNK - 1) / CHUNK;

    // ---- CSR build: 1-pass partition into fixed segments + finalize ----
    hipMemsetAsync(bucket_cnt, 0, MAXBUCK * sizeof(int), stream);
    k_partition<<<nchunk, 256, 0, stream>>>(arows, acols, avals, bucket_cnt,
                                            part, E, nbuck);
    k_scan2<<<1, 1024, 0, stream>>>(bucket_cnt, bucket_base, nbuck);
    k_build_csr<<<nbuck, 256, 0, stream>>>(part, bucket_cnt, bucket_base,
                                           row_ptr, csr, N, E);

    const int nTiles = (N + 15) / 16;
    const int gemm_blocks = 782;
    const int spmm_blocks = (N + 3) / 4;

    // layer 0: Out = emb*scale + norm0*scale
    k_gemm_mfma<true><<<gemm_blocks, 256, 0, stream>>>(emb, wts, Y8, nTiles, N);
    k_spmm_norm<<<spmm_blocks, 256, 0, stream>>>(row_ptr, csr, Y8, bufX,
                                                 out, emb, scale, scale, 1, N);
    // layers 1..L-1: Out += norm_l*scale
    for (int l = 1; l < L; ++l) {
        k_gemm_mfma<false><<<gemm_blocks, 256, 0, stream>>>(
            bufX, wts + (size_t)l * EMB * EMB, Y8, nTiles, N);
        k_spmm_norm<<<spmm_blocks, 256, 0, stream>>>(row_ptr, csr, Y8, bufX,
                                                     out, out, 1.0f, scale,
                                                     (l < L - 1) ? 1 : 0, N);
    }
}

// Round 12
// 851.497 us; speedup vs baseline: 1.0474x; 1.0474x over previous
//
#include <hip/hip_runtime.h>

#define EMB 100
#define XSTRIDE 52       // bf16 X row stride in dwords (16B-aligned rows)
#define Y8DW 32          // fp8 Y row stride in dwords (128 B, line-aligned)
#define BSHIFT 8         // bucket = row >> 8  (256 rows/bucket)
#define BROWS 256
#define MAXBUCK 1024
#define CAP 9216         // fixed part-segment capacity per bucket (11-sigma slack)
#define CHUNK 4096       // edges per workgroup in partition
#define EPT (CHUNK / 256)

typedef __attribute__((ext_vector_type(8))) short short8;
typedef __attribute__((ext_vector_type(4))) float f32x4;
typedef __attribute__((ext_vector_type(2))) float f2v;

// ---- bf16 helpers ----
__device__ __forceinline__ unsigned packbf(float a, float b) {
    unsigned ua = __float_as_uint(a), ub = __float_as_uint(b);
    unsigned ra = (ua + 0x7FFFu + ((ua >> 16) & 1u)) >> 16;   // RNE
    unsigned rb = (ub + 0x7FFFu + ((ub >> 16) & 1u)) >> 16;
    return ra | (rb << 16);
}

// ---- fp8 e4m3 (OCP) helpers ----
__device__ __forceinline__ unsigned char f32_to_fp8(float f) {
    unsigned u = __float_as_uint(f);
    unsigned s = (u >> 24) & 0x80u;
    unsigned mag = u & 0x7FFFFFFFu;
    if (mag >= 0x43E00000u) return (unsigned char)(s | 0x7Eu);      // clamp 448
    if (mag < 0x3C800000u) {                                        // subnormal
        int r = __float2int_rn(__uint_as_float(mag) * 512.f);
        return (unsigned char)(s | (unsigned)r);
    }
    unsigned r = mag + 0x7FFFFu + ((mag >> 20) & 1u);               // RNE at bit 20
    unsigned e = r >> 23, m = (r >> 20) & 7u;
    return (unsigned char)(s | ((e - 120u) << 3) | m);
}

__device__ __forceinline__ unsigned pack4_fp8(float a0, float a1, float a2, float a3) {
#if __has_builtin(__builtin_amdgcn_cvt_pk_fp8_f32)
    int lo = __builtin_amdgcn_cvt_pk_fp8_f32(a0, a1, 0, false);
    return (unsigned)__builtin_amdgcn_cvt_pk_fp8_f32(a2, a3, lo, true);
#else
    return (unsigned)f32_to_fp8(a0) | ((unsigned)f32_to_fp8(a1) << 8) |
           ((unsigned)f32_to_fp8(a2) << 16) | ((unsigned)f32_to_fp8(a3) << 24);
#endif
}

__device__ __forceinline__ void fma_fp8x4(unsigned g, float v,
                                          float& a0, float& a1, float& a2, float& a3) {
#if __has_builtin(__builtin_amdgcn_cvt_pk_f32_fp8)
    f2v lo = __builtin_amdgcn_cvt_pk_f32_fp8((int)g, false);
    f2v hi = __builtin_amdgcn_cvt_pk_f32_fp8((int)g, true);
    a0 = fmaf(v, lo[0], a0); a1 = fmaf(v, lo[1], a1);
    a2 = fmaf(v, hi[0], a2); a3 = fmaf(v, hi[1], a3);
#else
    float o[4];
#pragma unroll
    for (int d = 0; d < 4; ++d) {
        unsigned b = (g >> (8 * d)) & 0xFFu;
        unsigned e = (b >> 3) & 15u, m = b & 7u;
        float val = e ? __uint_as_float(((e + 120u) << 23) | (m << 20))
                      : (float)m * (1.f / 512.f);
        o[d] = (b & 0x80u) ? -val : val;
    }
    a0 = fmaf(v, o[0], a0); a1 = fmaf(v, o[1], a1);
    a2 = fmaf(v, o[2], a2); a3 = fmaf(v, o[3], a3);
#endif
}

// ---------------- partition into fixed-capacity row-bucket segments ----------
__global__ __launch_bounds__(256) void k_partition(const int* __restrict__ rows,
                                                   const int* __restrict__ cols,
                                                   const float* __restrict__ vals,
                                                   int* __restrict__ bucket_cnt,
                                                   int2* __restrict__ part,
                                                   int E, int nbuck) {
    __shared__ int hist[MAXBUCK];
    __shared__ int loc[MAXBUCK];
    __shared__ int base_s[MAXBUCK];
    __shared__ int scan256[256];
    __shared__ int2 stage[CHUNK];      // 32 KB bucket-sorted staging
    int tid = threadIdx.x;
    int base = blockIdx.x * CHUNK;
    int nE = E - base; if (nE > CHUNK) nE = CHUNK;

    for (int s = tid; s < nbuck; s += 256) hist[s] = 0;
    __syncthreads();

    int r_[EPT]; unsigned cv_[EPT]; int rk_[EPT];
#pragma unroll
    for (int k = 0; k < EPT; ++k) {
        int o = tid + k * 256;
        if (o < nE) {
            int i = base + o;
            int r = rows[i];
            unsigned q = (unsigned)__float2int_rn(vals[i] * 16383.f);
            r_[k] = r;
            cv_[k] = (unsigned)cols[i] | (q << 18);
            rk_[k] = atomicAdd(&hist[r >> BSHIFT], 1);   // rank within (chunk,bucket)
        } else r_[k] = -1;
    }
    __syncthreads();

    for (int s = tid; s < nbuck; s += 256)
        base_s[s] = hist[s] ? atomicAdd(&bucket_cnt[s], hist[s]) : 0;

    int s4 = tid * 4;
    int h0 = (s4     < nbuck) ? hist[s4]     : 0;
    int h1 = (s4 + 1 < nbuck) ? hist[s4 + 1] : 0;
    int h2 = (s4 + 2 < nbuck) ? hist[s4 + 2] : 0;
    int h3 = (s4 + 3 < nbuck) ? hist[s4 + 3] : 0;
    int tot = h0 + h1 + h2 + h3;
    scan256[tid] = tot;
    __syncthreads();
    for (int off = 1; off < 256; off <<= 1) {
        int t = (tid >= off) ? scan256[tid - off] : 0;
        __syncthreads();
        scan256[tid] += t;
        __syncthreads();
    }
    int excl = scan256[tid] - tot;
    if (s4     < nbuck) loc[s4]     = excl;
    if (s4 + 1 < nbuck) loc[s4 + 1] = excl + h0;
    if (s4 + 2 < nbuck) loc[s4 + 2] = excl + h0 + h1;
    if (s4 + 3 < nbuck) loc[s4 + 3] = excl + h0 + h1 + h2;
    __syncthreads();

#pragma unroll
    for (int k = 0; k < EPT; ++k) {
        if (r_[k] >= 0) {
            int b = r_[k] >> BSHIFT;
            stage[loc[b] + rk_[k]] = make_int2(r_[k], (int)cv_[k]);
        }
    }
    __syncthreads();

    for (int k = tid; k < nE; k += 256) {
        int2 e = stage[k];
        int b = e.x >> BSHIFT;
        int pos = base_s[b] + (k - loc[b]);
        if (pos < CAP)   // statistically impossible overflow guard
            part[(size_t)b * CAP + pos] = e;
    }
}

// ---------------- exclusive scan of bucket counts -> csr bases ---------------
__global__ __launch_bounds__(1024) void k_scan2(const int* __restrict__ cnt,
                                                int* __restrict__ basearr, int nb) {
    __shared__ int tmp[1024];
    int v = (threadIdx.x < nb) ? cnt[threadIdx.x] : 0;
    tmp[threadIdx.x] = v;
    __syncthreads();
    for (int off = 1; off < 1024; off <<= 1) {
        int t = (threadIdx.x >= off) ? tmp[threadIdx.x - off] : 0;
        __syncthreads();
        tmp[threadIdx.x] += t;
        __syncthreads();
    }
    if (threadIdx.x < nb) basearr[threadIdx.x] = tmp[threadIdx.x] - v; // exclusive
}

// ---------------- per-bucket CSR finalize ----------------
__global__ __launch_bounds__(256) void k_build_csr(const int2* __restrict__ part,
                                                   const int* __restrict__ bucket_cnt,
                                                   const int* __restrict__ bucket_base,
                                                   int* __restrict__ row_ptr,
                                                   unsigned* __restrict__ csr,
                                                   int N, int E) {
    __shared__ int cnt[BROWS];
    __shared__ int scn[BROWS];
    __shared__ int cur[BROWS];
    int b = blockIdx.x;
    int tid = threadIdx.x;
    int cntb = bucket_cnt[b];
    const int2* seg = part + (size_t)b * CAP;
    int cbase = bucket_base[b];
    int rowbase = b << BSHIFT;

    cnt[tid] = 0;
    __syncthreads();
    for (int i = tid; i < cntb; i += 256)
        atomicAdd(&cnt[seg[i].x - rowbase], 1);
    __syncthreads();
    int v = cnt[tid];
    scn[tid] = v;
    __syncthreads();
    for (int off = 1; off < 256; off <<= 1) {
        int t = (tid >= off) ? scn[tid - off] : 0;
        __syncthreads();
        scn[tid] += t;
        __syncthreads();
    }
    int rp = cbase + scn[tid] - v;            // global exclusive
    if (rowbase + tid < N) row_ptr[rowbase + tid] = rp;
    cur[tid] = rp;
    if (b == 0 && tid == 0) row_ptr[N] = E;
    __syncthreads();
    for (int i = tid; i < cntb; i += 256) {
        int2 e = seg[i];
        int pos = atomicAdd(&cur[e.x - rowbase], 1);
        csr[pos] = (unsigned)e.y;
    }
}

// ---------------- MFMA GEMM: Y8[r][e] = fp8( sum_d X[r][d] * W[e][d] ) --------
// Swapped operands: lane holds row's 4 consecutive e -> 1 packed dword store.
// Zeroes the FULL row pad (dwords 25..31) so spmm's 16B gathers are clean.
template <bool F32SRC>
__global__ __launch_bounds__(256) void k_gemm_mfma(const void* __restrict__ Xv,
                                                   const float* __restrict__ W,
                                                   unsigned* __restrict__ Y8,
                                                   int nTiles, int N) {
    __shared__ uint4 Bf[28][64];   // [nt*4+ks][lane]  W fragments (bf16)
    int tid = threadIdx.x;
#pragma unroll
    for (int it = 0; it < 7; ++it) {
        int id = it * 256 + tid;
        int fs = id >> 6, lane = id & 63;
        int nt = fs >> 2, ks = fs & 3;
        int e = nt * 16 + (lane & 15);
        int dbase = ks * 32 + (lane >> 4) * 8;
        float w[8];
#pragma unroll
        for (int j = 0; j < 8; ++j) {
            int d = dbase + j;
            w[j] = (e < EMB && d < EMB) ? W[e * EMB + d] : 0.f;
        }
        uint4 u;
        u.x = packbf(w[0], w[1]); u.y = packbf(w[2], w[3]);
        u.z = packbf(w[4], w[5]); u.w = packbf(w[6], w[7]);
        Bf[fs][lane] = u;
    }
    __syncthreads();

    int wid = (blockIdx.x * 256 + tid) >> 6;
    int nWaves = gridDim.x * 4;
    int lane = tid & 63;
    int m = lane & 15, kg = lane >> 4;

    for (int tile = wid; tile < nTiles; tile += nWaves) {
        int rowbase = tile * 16;
        int arow = rowbase + m; if (arow >= N) arow = N - 1;   // clamp
        uint4 a[4];
        if (F32SRC) {
            const float* xr = (const float*)Xv + (size_t)arow * EMB;
#pragma unroll
            for (int ks = 0; ks < 3; ++ks) {
                float4 v0 = *(const float4*)(xr + ks * 32 + kg * 8);
                float4 v1 = *(const float4*)(xr + ks * 32 + kg * 8 + 4);
                a[ks] = make_uint4(packbf(v0.x, v0.y), packbf(v0.z, v0.w),
                                   packbf(v1.x, v1.y), packbf(v1.z, v1.w));
            }
            uint4 t = make_uint4(0, 0, 0, 0);
            if (kg == 0) { float4 v = *(const float4*)(xr + 96);
                           t.x = packbf(v.x, v.y); t.y = packbf(v.z, v.w); }
            a[3] = t;
        } else {
            const unsigned* xr = (const unsigned*)Xv + (size_t)arow * XSTRIDE;
#pragma unroll
            for (int ks = 0; ks < 3; ++ks)
                a[ks] = *(const uint4*)(xr + ks * 16 + kg * 4);
            uint4 t = make_uint4(0, 0, 0, 0);
            if (kg == 0) { uint2 v = *(const uint2*)(xr + 48); t.x = v.x; t.y = v.y; }
            a[3] = t;
        }

        f32x4 acc[7];
#pragma unroll
        for (int nt = 0; nt < 7; ++nt) acc[nt] = (f32x4){0.f, 0.f, 0.f, 0.f};
#pragma unroll
        for (int ks = 0; ks < 4; ++ks) {
            short8 av = __builtin_bit_cast(short8, a[ks]);
#pragma unroll
            for (int nt = 0; nt < 7; ++nt) {
                short8 bv = __builtin_bit_cast(short8, Bf[nt * 4 + ks][lane]);
                acc[nt] = __builtin_amdgcn_mfma_f32_16x16x32_bf16(bv, av, acc[nt], 0, 0, 0);
            }
        }
        int rr = rowbase + m;
        if (rr < N) {
            unsigned* yrow = Y8 + ((size_t)rr << 5) + kg;
#pragma unroll
            for (int nt = 0; nt < 6; ++nt)
                yrow[nt * 4] = pack4_fp8(acc[nt][0], acc[nt][1], acc[nt][2], acc[nt][3]);
            if (kg == 0)
                yrow[24] = pack4_fp8(acc[6][0], acc[6][1], acc[6][2], acc[6][3]);
            else
                yrow[24] = 0;   // dwords 25,26,27 = 0
            yrow[28] = 0;       // dwords 28..31 = 0
        }
    }
}

// ---------------- SpMM + norm + mean-accumulate (fp8 dwordx4 gather) ---------
// One wave per row; 8 groups x 8 lanes; group g takes edges j==g mod 8;
// lane lg gathers 16 B (dims 16lg..15; pad zeroed by GEMM). 32-edge MASKED
// rounds (4-unroll x 8 groups): every edge runs at full MLP, no serial tail.
// dq deferred to the epilogue.
__global__ __launch_bounds__(256) void k_spmm_norm(const int* __restrict__ row_ptr,
                                                   const unsigned* __restrict__ csr,
                                                   const unsigned* __restrict__ Y8,
                                                   unsigned* __restrict__ Xout,
                                                   float* __restrict__ Out,
                                                   const float* __restrict__ prev,
                                                   float pscale, float scale,
                                                   int writeX, int N) {
    int wave = (blockIdx.x * 256 + threadIdx.x) >> 6;
    int lane = threadIdx.x & 63;
    if (wave >= N) return;
    int g = lane >> 3, lg = lane & 7;
    int beg = row_ptr[wave], end = row_ptr[wave + 1];
    const float dq = 1.0f / 16383.f;
    float a[16];
#pragma unroll
    for (int k = 0; k < 16; ++k) a[k] = 0.f;
    const uint4* Yb = (const uint4*)((const char*)Y8 + lg * 16);

    for (int j0 = beg; j0 < end; j0 += 32) {
#pragma unroll
        for (int t = 0; t < 4; ++t) {
            int je = j0 + t * 8 + g;
            bool ok = je < end;
            unsigned u = __builtin_nontemporal_load(&csr[ok ? je : beg]);
            float v = ok ? (float)(u >> 18) : 0.f;
            uint4 gg = Yb[(size_t)(u & 0x3FFFFu) << 3];
            fma_fp8x4(gg.x, v, a[0], a[1], a[2], a[3]);
            fma_fp8x4(gg.y, v, a[4], a[5], a[6], a[7]);
            fma_fp8x4(gg.z, v, a[8], a[9], a[10], a[11]);
            fma_fp8x4(gg.w, v, a[12], a[13], a[14], a[15]);
        }
    }

    // reduce across the 8 groups (same lg across groups holds same dims)
#pragma unroll
    for (int k = 0; k < 16; ++k) {
        float t = a[k];
        t += __shfl_xor(t, 8, 64);
        t += __shfl_xor(t, 16, 64);
        t += __shfl_xor(t, 32, 64);
        a[k] = t;
    }
    float ss = 0.f;
#pragma unroll
    for (int k = 0; k < 16; ++k) ss = fmaf(a[k], a[k], ss);   // pad dims are 0
    ss += __shfl_xor(ss, 1, 64);
    ss += __shfl_xor(ss, 2, 64);
    ss += __shfl_xor(ss, 4, 64);
    // a[] are scaled by 16383; fold dq into the output scale
    float so = scale / fmaxf(sqrtf(ss), 1e-8f);

    // epilogue: lanes 0..31; lane (g<4, lg) owns dims lg*16 + g*4 .. +3
    if (lane < 32) {
        int dbase = lg * 16 + g * 4;
        if (dbase < EMB) {
            float w0 = a[g * 4 + 0], w1 = a[g * 4 + 1];
            float w2 = a[g * 4 + 2], w3 = a[g * 4 + 3];
            if (writeX) {
                uint2 xw;
                xw.x = packbf(w0 * dq, w1 * dq);
                xw.y = packbf(w2 * dq, w3 * dq);
                *(uint2*)(Xout + (size_t)wave * XSTRIDE + (dbase >> 1)) = xw;
            }
            float4 p = *(const float4*)(prev + (size_t)wave * EMB + dbase);
            float4 o;
            o.x = fmaf(w0, so, p.x * pscale);
            o.y = fmaf(w1, so, p.y * pscale);
            o.z = fmaf(w2, so, p.z * pscale);
            o.w = fmaf(w3, so, p.w * pscale);
            *(float4*)(Out + (size_t)wave * EMB + dbase) = o;
        }
    }
}

extern "C" void kernel_launch(void* const* d_in, const int* in_sizes, int n_in,
                              void* d_out, int out_size, void* d_ws, size_t ws_size,
                              hipStream_t stream) {
    const float* emb   = (const float*)d_in[0];
    const float* avals = (const float*)d_in[1];
    const float* wts   = (const float*)d_in[2];
    const int*   arows = (const int*)d_in[3];
    const int*   acols = (const int*)d_in[4];

    const int N = in_sizes[0] / EMB;
    const int E = in_sizes[1];
    const int L = in_sizes[2] / (EMB * EMB);
    const float scale = 1.0f / (float)(L + 1);
    const int nbuck = (N + BROWS - 1) >> BSHIFT;

    // workspace layout (dwords). part (nbuck*CAP int2) aliases Y8+bufX.
    unsigned* Y8      = (unsigned*)d_ws;                     // N*Y8DW (fp8 rows)
    unsigned* bufX    = Y8 + (size_t)N * Y8DW;               // N*XSTRIDE (bf16)
    int* row_ptr      = (int*)(bufX + (size_t)N * XSTRIDE);  // N+2
    int* bucket_cnt   = row_ptr + (N + 2);                   // MAXBUCK
    int* bucket_base  = bucket_cnt + MAXBUCK;                // MAXBUCK
    unsigned* csr     = (unsigned*)(bucket_base + MAXBUCK);  // E
    int2* part        = (int2*)d_ws;                         // nbuck*CAP (aliased)
    float* out = (float*)d_out;

    const int nchunk = (E + CHUNK - 1) / CHUNK;

    // ---- CSR build: 1-pass partition into fixed segments + finalize ----
    hipMemsetAsync(bucket_cnt, 0, MAXBUCK * sizeof(int), stream);
    k_partition<<<nchunk, 256, 0, stream>>>(arows, acols, avals, bucket_cnt,
                                            part, E, nbuck);
    k_scan2<<<1, 1024, 0, stream>>>(bucket_cnt, bucket_base, nbuck);
    k_build_csr<<<nbuck, 256, 0, stream>>>(part, bucket_cnt, bucket_base,
                                           row_ptr, csr, N, E);

    const int nTiles = (N + 15) / 16;
    const int gemm_blocks = 782;
    const int spmm_blocks = (N + 3) / 4;

    // layer 0: Out = emb*scale + norm0*scale
    k_gemm_mfma<true><<<gemm_blocks, 256, 0, stream>>>(emb, wts, Y8, nTiles, N);
    k_spmm_norm<<<spmm_blocks, 256, 0, stream>>>(row_ptr, csr, Y8, bufX,
                                                 out, emb, scale, scale, 1, N);
    // layers 1..L-1: Out += norm_l*scale
    for (int l = 1; l < L; ++l) {
        k_gemm_mfma<false><<<gemm_blocks, 256, 0, stream>>>(
            bufX, wts + (size_t)l * EMB * EMB, Y8, nTiles, N);
        k_spmm_norm<<<spmm_blocks, 256, 0, stream>>>(row_ptr, csr, Y8, bufX,
                                                     out, out, 1.0f, scale,
                                                     (l < L - 1) ? 1 : 0, N);
    }
}

// Round 13
// 785.789 us; speedup vs baseline: 1.1350x; 1.0836x over previous
//
#include <hip/hip_runtime.h>

#define EMB 100
#define XSTRIDE 52       // bf16 X row stride in dwords (16B-aligned rows)
#define Y8DW 32          // fp8 Y row stride in dwords (128 B, line-aligned)
#define BSHIFT 8         // bucket = row >> 8  (256 rows/bucket)
#define BROWS 256
#define MAXBUCK 1024
#define CAP 9216         // fixed part-segment capacity per bucket (11-sigma slack)
#define CHUNK 4096       // edges per workgroup in partition
#define EPT (CHUNK / 256)

typedef __attribute__((ext_vector_type(8))) short short8;
typedef __attribute__((ext_vector_type(4))) float f32x4;
typedef __attribute__((ext_vector_type(2))) float f2v;

// ---- bf16 helpers ----
__device__ __forceinline__ unsigned packbf(float a, float b) {
    unsigned ua = __float_as_uint(a), ub = __float_as_uint(b);
    unsigned ra = (ua + 0x7FFFu + ((ua >> 16) & 1u)) >> 16;   // RNE
    unsigned rb = (ub + 0x7FFFu + ((ub >> 16) & 1u)) >> 16;
    return ra | (rb << 16);
}

// ---- fp8 e4m3 (OCP) helpers ----
__device__ __forceinline__ unsigned char f32_to_fp8(float f) {
    unsigned u = __float_as_uint(f);
    unsigned s = (u >> 24) & 0x80u;
    unsigned mag = u & 0x7FFFFFFFu;
    if (mag >= 0x43E00000u) return (unsigned char)(s | 0x7Eu);      // clamp 448
    if (mag < 0x3C800000u) {                                        // subnormal
        int r = __float2int_rn(__uint_as_float(mag) * 512.f);
        return (unsigned char)(s | (unsigned)r);
    }
    unsigned r = mag + 0x7FFFFu + ((mag >> 20) & 1u);               // RNE at bit 20
    unsigned e = r >> 23, m = (r >> 20) & 7u;
    return (unsigned char)(s | ((e - 120u) << 3) | m);
}

__device__ __forceinline__ unsigned pack4_fp8(float a0, float a1, float a2, float a3) {
#if __has_builtin(__builtin_amdgcn_cvt_pk_fp8_f32)
    int lo = __builtin_amdgcn_cvt_pk_fp8_f32(a0, a1, 0, false);
    return (unsigned)__builtin_amdgcn_cvt_pk_fp8_f32(a2, a3, lo, true);
#else
    return (unsigned)f32_to_fp8(a0) | ((unsigned)f32_to_fp8(a1) << 8) |
           ((unsigned)f32_to_fp8(a2) << 16) | ((unsigned)f32_to_fp8(a3) << 24);
#endif
}

__device__ __forceinline__ void fma_fp8x4(unsigned g, float v,
                                          float& a0, float& a1, float& a2, float& a3) {
#if __has_builtin(__builtin_amdgcn_cvt_pk_f32_fp8)
    f2v lo = __builtin_amdgcn_cvt_pk_f32_fp8((int)g, false);
    f2v hi = __builtin_amdgcn_cvt_pk_f32_fp8((int)g, true);
    a0 = fmaf(v, lo[0], a0); a1 = fmaf(v, lo[1], a1);
    a2 = fmaf(v, hi[0], a2); a3 = fmaf(v, hi[1], a3);
#else
    float o[4];
#pragma unroll
    for (int d = 0; d < 4; ++d) {
        unsigned b = (g >> (8 * d)) & 0xFFu;
        unsigned e = (b >> 3) & 15u, m = b & 7u;
        float val = e ? __uint_as_float(((e + 120u) << 23) | (m << 20))
                      : (float)m * (1.f / 512.f);
        o[d] = (b & 0x80u) ? -val : val;
    }
    a0 = fmaf(v, o[0], a0); a1 = fmaf(v, o[1], a1);
    a2 = fmaf(v, o[2], a2); a3 = fmaf(v, o[3], a3);
#endif
}

// ---------------- partition into fixed-capacity row-bucket segments ----------
// One pass over COO; pass-1 LDS-hist atomic return value IS the within-chunk
// rank; LDS bucket-sorted stage -> coalesced segment writes.
__global__ __launch_bounds__(256) void k_partition(const int* __restrict__ rows,
                                                   const int* __restrict__ cols,
                                                   const float* __restrict__ vals,
                                                   int* __restrict__ bucket_cnt,
                                                   int2* __restrict__ part,
                                                   int E, int nbuck) {
    __shared__ int hist[MAXBUCK];
    __shared__ int loc[MAXBUCK];
    __shared__ int base_s[MAXBUCK];
    __shared__ int scan256[256];
    __shared__ int2 stage[CHUNK];      // 32 KB bucket-sorted staging
    int tid = threadIdx.x;
    int base = blockIdx.x * CHUNK;
    int nE = E - base; if (nE > CHUNK) nE = CHUNK;

    for (int s = tid; s < nbuck; s += 256) hist[s] = 0;
    __syncthreads();

    int r_[EPT]; unsigned cv_[EPT]; int rk_[EPT];
#pragma unroll
    for (int k = 0; k < EPT; ++k) {
        int o = tid + k * 256;
        if (o < nE) {
            int i = base + o;
            int r = rows[i];
            unsigned q = (unsigned)__float2int_rn(vals[i] * 16383.f);
            r_[k] = r;
            cv_[k] = (unsigned)cols[i] | (q << 18);
            rk_[k] = atomicAdd(&hist[r >> BSHIFT], 1);   // rank within (chunk,bucket)
        } else r_[k] = -1;
    }
    __syncthreads();

    for (int s = tid; s < nbuck; s += 256)
        base_s[s] = hist[s] ? atomicAdd(&bucket_cnt[s], hist[s]) : 0;

    int s4 = tid * 4;
    int h0 = (s4     < nbuck) ? hist[s4]     : 0;
    int h1 = (s4 + 1 < nbuck) ? hist[s4 + 1] : 0;
    int h2 = (s4 + 2 < nbuck) ? hist[s4 + 2] : 0;
    int h3 = (s4 + 3 < nbuck) ? hist[s4 + 3] : 0;
    int tot = h0 + h1 + h2 + h3;
    scan256[tid] = tot;
    __syncthreads();
    for (int off = 1; off < 256; off <<= 1) {
        int t = (tid >= off) ? scan256[tid - off] : 0;
        __syncthreads();
        scan256[tid] += t;
        __syncthreads();
    }
    int excl = scan256[tid] - tot;
    if (s4     < nbuck) loc[s4]     = excl;
    if (s4 + 1 < nbuck) loc[s4 + 1] = excl + h0;
    if (s4 + 2 < nbuck) loc[s4 + 2] = excl + h0 + h1;
    if (s4 + 3 < nbuck) loc[s4 + 3] = excl + h0 + h1 + h2;
    __syncthreads();

#pragma unroll
    for (int k = 0; k < EPT; ++k) {
        if (r_[k] >= 0) {
            int b = r_[k] >> BSHIFT;
            stage[loc[b] + rk_[k]] = make_int2(r_[k], (int)cv_[k]);
        }
    }
    __syncthreads();

    for (int k = tid; k < nE; k += 256) {
        int2 e = stage[k];
        int b = e.x >> BSHIFT;
        int pos = base_s[b] + (k - loc[b]);
        if (pos < CAP)   // statistically impossible overflow guard
            part[(size_t)b * CAP + pos] = e;
    }
}

// ---------------- exclusive scan of bucket counts -> csr bases ---------------
__global__ __launch_bounds__(1024) void k_scan2(const int* __restrict__ cnt,
                                                int* __restrict__ basearr, int nb) {
    __shared__ int tmp[1024];
    int v = (threadIdx.x < nb) ? cnt[threadIdx.x] : 0;
    tmp[threadIdx.x] = v;
    __syncthreads();
    for (int off = 1; off < 1024; off <<= 1) {
        int t = (threadIdx.x >= off) ? tmp[threadIdx.x - off] : 0;
        __syncthreads();
        tmp[threadIdx.x] += t;
        __syncthreads();
    }
    if (threadIdx.x < nb) basearr[threadIdx.x] = tmp[threadIdx.x] - v; // exclusive
}

// ---------------- per-bucket CSR finalize ----------------
__global__ __launch_bounds__(256) void k_build_csr(const int2* __restrict__ part,
                                                   const int* __restrict__ bucket_cnt,
                                                   const int* __restrict__ bucket_base,
                                                   int* __restrict__ row_ptr,
                                                   unsigned* __restrict__ csr,
                                                   int N, int E) {
    __shared__ int cnt[BROWS];
    __shared__ int scn[BROWS];
    __shared__ int cur[BROWS];
    int b = blockIdx.x;
    int tid = threadIdx.x;
    int cntb = bucket_cnt[b];
    const int2* seg = part + (size_t)b * CAP;
    int cbase = bucket_base[b];
    int rowbase = b << BSHIFT;

    cnt[tid] = 0;
    __syncthreads();
    for (int i = tid; i < cntb; i += 256)
        atomicAdd(&cnt[seg[i].x - rowbase], 1);
    __syncthreads();
    int v = cnt[tid];
    scn[tid] = v;
    __syncthreads();
    for (int off = 1; off < 256; off <<= 1) {
        int t = (tid >= off) ? scn[tid - off] : 0;
        __syncthreads();
        scn[tid] += t;
        __syncthreads();
    }
    int rp = cbase + scn[tid] - v;            // global exclusive
    if (rowbase + tid < N) row_ptr[rowbase + tid] = rp;
    cur[tid] = rp;
    if (b == 0 && tid == 0) row_ptr[N] = E;
    __syncthreads();
    for (int i = tid; i < cntb; i += 256) {
        int2 e = seg[i];
        int pos = atomicAdd(&cur[e.x - rowbase], 1);
        csr[pos] = (unsigned)e.y;
    }
}

// ---------------- MFMA GEMM: Y8[r][e] = fp8( sum_d X[r][d] * W[e][d] ) --------
// Swapped operands: lane holds row's 4 consecutive e -> 1 packed dword store.
// Only dwords 0..24 are read by spmm; pad stores dropped.
template <bool F32SRC>
__global__ __launch_bounds__(256) void k_gemm_mfma(const void* __restrict__ Xv,
                                                   const float* __restrict__ W,
                                                   unsigned* __restrict__ Y8,
                                                   int nTiles, int N) {
    __shared__ uint4 Bf[28][64];   // [nt*4+ks][lane]  W fragments (bf16)
    int tid = threadIdx.x;
#pragma unroll
    for (int it = 0; it < 7; ++it) {
        int id = it * 256 + tid;
        int fs = id >> 6, lane = id & 63;
        int nt = fs >> 2, ks = fs & 3;
        int e = nt * 16 + (lane & 15);
        int dbase = ks * 32 + (lane >> 4) * 8;
        float w[8];
#pragma unroll
        for (int j = 0; j < 8; ++j) {
            int d = dbase + j;
            w[j] = (e < EMB && d < EMB) ? W[e * EMB + d] : 0.f;
        }
        uint4 u;
        u.x = packbf(w[0], w[1]); u.y = packbf(w[2], w[3]);
        u.z = packbf(w[4], w[5]); u.w = packbf(w[6], w[7]);
        Bf[fs][lane] = u;
    }
    __syncthreads();

    int wid = (blockIdx.x * 256 + tid) >> 6;
    int nWaves = gridDim.x * 4;
    int lane = tid & 63;
    int m = lane & 15, kg = lane >> 4;

    for (int tile = wid; tile < nTiles; tile += nWaves) {
        int rowbase = tile * 16;
        int arow = rowbase + m; if (arow >= N) arow = N - 1;   // clamp
        uint4 a[4];
        if (F32SRC) {
            const float* xr = (const float*)Xv + (size_t)arow * EMB;
#pragma unroll
            for (int ks = 0; ks < 3; ++ks) {
                float4 v0 = *(const float4*)(xr + ks * 32 + kg * 8);
                float4 v1 = *(const float4*)(xr + ks * 32 + kg * 8 + 4);
                a[ks] = make_uint4(packbf(v0.x, v0.y), packbf(v0.z, v0.w),
                                   packbf(v1.x, v1.y), packbf(v1.z, v1.w));
            }
            uint4 t = make_uint4(0, 0, 0, 0);
            if (kg == 0) { float4 v = *(const float4*)(xr + 96);
                           t.x = packbf(v.x, v.y); t.y = packbf(v.z, v.w); }
            a[3] = t;
        } else {
            const unsigned* xr = (const unsigned*)Xv + (size_t)arow * XSTRIDE;
#pragma unroll
            for (int ks = 0; ks < 3; ++ks)
                a[ks] = *(const uint4*)(xr + ks * 16 + kg * 4);
            uint4 t = make_uint4(0, 0, 0, 0);
            if (kg == 0) { uint2 v = *(const uint2*)(xr + 48); t.x = v.x; t.y = v.y; }
            a[3] = t;
        }

        f32x4 acc[7];
#pragma unroll
        for (int nt = 0; nt < 7; ++nt) acc[nt] = (f32x4){0.f, 0.f, 0.f, 0.f};
#pragma unroll
        for (int ks = 0; ks < 4; ++ks) {
            short8 av = __builtin_bit_cast(short8, a[ks]);
#pragma unroll
            for (int nt = 0; nt < 7; ++nt) {
                short8 bv = __builtin_bit_cast(short8, Bf[nt * 4 + ks][lane]);
                acc[nt] = __builtin_amdgcn_mfma_f32_16x16x32_bf16(bv, av, acc[nt], 0, 0, 0);
            }
        }
        // epilogue: lane owns row rowbase+m, e-block nt*16+kg*4..+3
        int rr = rowbase + m;
        if (rr < N) {
            unsigned* yrow = Y8 + ((size_t)rr << 5) + kg;
#pragma unroll
            for (int nt = 0; nt < 6; ++nt)
                yrow[nt * 4] = pack4_fp8(acc[nt][0], acc[nt][1], acc[nt][2], acc[nt][3]);
            if (kg == 0)
                yrow[24] = pack4_fp8(acc[6][0], acc[6][1], acc[6][2], acc[6][3]);
        }
    }
}

// ---------------- SpMM + norm + mean-accumulate (fp8 dword gather) -----------
// r9 structure (measured best): one wave per row, two 32-lane halves; each
// half processes one edge with 25 active lanes x 4 fp8 dims (1 dword
// gather/lane); 8 edges in flight per lane.
__global__ __launch_bounds__(256) void k_spmm_norm(const int* __restrict__ row_ptr,
                                                   const unsigned* __restrict__ csr,
                                                   const unsigned* __restrict__ Y8,
                                                   unsigned* __restrict__ Xout,
                                                   float* __restrict__ Out,
                                                   const float* __restrict__ prev,
                                                   float pscale, float scale,
                                                   int writeX, int N) {
    int wave = (blockIdx.x * 256 + threadIdx.x) >> 6;
    int lane = threadIdx.x & 63;
    if (wave >= N) return;
    int half = lane >> 5, sub = lane & 31;
    int beg = row_ptr[wave], end = row_ptr[wave + 1];
    const float dq = 1.0f / 16383.f;
    float a0 = 0.f, a1 = 0.f, a2 = 0.f, a3 = 0.f;
    if (sub < 25) {
        const unsigned* yb = Y8 + sub;
        int j = beg + half;
        for (; j + 14 < end; j += 16) {
            unsigned u[8], g[8];
#pragma unroll
            for (int t = 0; t < 8; ++t)
                u[t] = __builtin_nontemporal_load(&csr[j + 2 * t]);
#pragma unroll
            for (int t = 0; t < 8; ++t)
                g[t] = yb[(u[t] & 0x3FFFFu) << 5];
#pragma unroll
            for (int t = 0; t < 8; ++t)
                fma_fp8x4(g[t], (float)(u[t] >> 18) * dq, a0, a1, a2, a3);
        }
        for (; j + 6 < end; j += 8) {
            unsigned u[4], g[4];
#pragma unroll
            for (int t = 0; t < 4; ++t)
                u[t] = __builtin_nontemporal_load(&csr[j + 2 * t]);
#pragma unroll
            for (int t = 0; t < 4; ++t)
                g[t] = yb[(u[t] & 0x3FFFFu) << 5];
#pragma unroll
            for (int t = 0; t < 4; ++t)
                fma_fp8x4(g[t], (float)(u[t] >> 18) * dq, a0, a1, a2, a3);
        }
        for (; j < end; j += 2) {
            unsigned u = csr[j];
            unsigned g = yb[(u & 0x3FFFFu) << 5];
            float v = (float)(u >> 18) * dq;
            fma_fp8x4(g, v, a0, a1, a2, a3);
        }
    }
    // combine the two half-wave partial sums (lane l <-> l+32)
    a0 += __shfl_xor(a0, 32, 64);
    a1 += __shfl_xor(a1, 32, 64);
    a2 += __shfl_xor(a2, 32, 64);
    a3 += __shfl_xor(a3, 32, 64);
    float ss = fmaf(a0, a0, fmaf(a1, a1, fmaf(a2, a2, a3 * a3)));
#pragma unroll
    for (int off = 16; off; off >>= 1) ss += __shfl_xor(ss, off, 64);
    float sc = scale / fmaxf(sqrtf(ss), 1e-12f);
    if (half == 0 && sub < 25) {
        if (writeX) {
            uint2 xw;
            xw.x = packbf(a0, a1); xw.y = packbf(a2, a3);
            *(uint2*)(Xout + (size_t)wave * XSTRIDE + sub * 2) = xw;
        }
        const float4* pp = (const float4*)(prev + (size_t)wave * EMB) + sub;
        float4 p = *pp;
        float4 o;
        o.x = fmaf(a0, sc, p.x * pscale);
        o.y = fmaf(a1, sc, p.y * pscale);
        o.z = fmaf(a2, sc, p.z * pscale);
        o.w = fmaf(a3, sc, p.w * pscale);
        *((float4*)(Out + (size_t)wave * EMB) + sub) = o;
    }
}

extern "C" void kernel_launch(void* const* d_in, const int* in_sizes, int n_in,
                              void* d_out, int out_size, void* d_ws, size_t ws_size,
                              hipStream_t stream) {
    const float* emb   = (const float*)d_in[0];
    const float* avals = (const float*)d_in[1];
    const float* wts   = (const float*)d_in[2];
    const int*   arows = (const int*)d_in[3];
    const int*   acols = (const int*)d_in[4];

    const int N = in_sizes[0] / EMB;
    const int E = in_sizes[1];
    const int L = in_sizes[2] / (EMB * EMB);
    const float scale = 1.0f / (float)(L + 1);
    const int nbuck = (N + BROWS - 1) >> BSHIFT;

    // workspace layout (dwords). part (nbuck*CAP int2) aliases Y8+bufX.
    unsigned* Y8      = (unsigned*)d_ws;                     // N*Y8DW (fp8 rows)
    unsigned* bufX    = Y8 + (size_t)N * Y8DW;               // N*XSTRIDE (bf16)
    int* row_ptr      = (int*)(bufX + (size_t)N * XSTRIDE);  // N+2
    int* bucket_cnt   = row_ptr + (N + 2);                   // MAXBUCK
    int* bucket_base  = bucket_cnt + MAXBUCK;                // MAXBUCK
    unsigned* csr     = (unsigned*)(bucket_base + MAXBUCK);  // E
    int2* part        = (int2*)d_ws;                         // nbuck*CAP (aliased)
    float* out = (float*)d_out;

    const int nchunk = (E + CHUNK - 1) / CHUNK;

    // ---- CSR build: 1-pass partition into fixed segments + finalize ----
    hipMemsetAsync(bucket_cnt, 0, MAXBUCK * sizeof(int), stream);
    k_partition<<<nchunk, 256, 0, stream>>>(arows, acols, avals, bucket_cnt,
                                            part, E, nbuck);
    k_scan2<<<1, 1024, 0, stream>>>(bucket_cnt, bucket_base, nbuck);
    k_build_csr<<<nbuck, 256, 0, stream>>>(part, bucket_cnt, bucket_base,
                                           row_ptr, csr, N, E);

    const int nTiles = (N + 15) / 16;
    const int gemm_blocks = 782;
    const int spmm_blocks = (N + 3) / 4;

    // layer 0: Out = emb*scale + norm0*scale
    k_gemm_mfma<true><<<gemm_blocks, 256, 0, stream>>>(emb, wts, Y8, nTiles, N);
    k_spmm_norm<<<spmm_blocks, 256, 0, stream>>>(row_ptr, csr, Y8, bufX,
                                                 out, emb, scale, scale, 1, N);
    // layers 1..L-1: Out += norm_l*scale
    for (int l = 1; l < L; ++l) {
        k_gemm_mfma<false><<<gemm_blocks, 256, 0, stream>>>(
            bufX, wts + (size_t)l * EMB * EMB, Y8, nTiles, N);
        k_spmm_norm<<<spmm_blocks, 256, 0, stream>>>(row_ptr, csr, Y8, bufX,
                                                     out, out, 1.0f, scale,
                                                     (l < L - 1) ? 1 : 0, N);
    }
}